// Round 1
// baseline (1785.389 us; speedup 1.0000x reference)
//
#include <hip/hip_runtime.h>
#include <hip/hip_bf16.h>
#include <cfloat>

#define LNUM 4
#define BNUM 16
#define DNUM 768
#define SNUM 1000   // T*F = 125*8
#define KNUM 1000
#define KTNUM 512
#define KPAD 1024

// ---------------- c2 = rowwise ||c||^2 ----------------
__global__ void c2_kernel(const float* __restrict__ centers, float* __restrict__ c2) {
    int row  = blockIdx.x;           // 0..L*K-1
    int lane = threadIdx.x;          // 0..63
    const float* cr = centers + (size_t)row * DNUM;
    float s = 0.f;
    for (int d = lane; d < DNUM; d += 64) s += cr[d] * cr[d];
#pragma unroll
    for (int m = 32; m >= 1; m >>= 1) s += __shfl_xor(s, m);
    if (lane == 0) c2[row] = s;
}

// ---------------- fused distance-GEMM + column argmin(top2) ----------------
__global__ __launch_bounds__(256, 4)
void token_kernel(const float* __restrict__ h, const float* __restrict__ centers,
                  const float* __restrict__ c2g, float* __restrict__ out_tokens_f,
                  int* __restrict__ ws_tokens) {
    __shared__ float At[32][68];   // [d][k], padded stride 68 (16B-aligned rows, conflict-spread)
    __shared__ float Bt[32][68];   // [d][s]

    const int stile = blockIdx.x;          // 0..15 (s tiles of 64)
    const int lb    = blockIdx.y;          // 0..63 == l*16 + b
    const int l     = lb >> 4;
    const int bi    = lb & 15;
    const int s0    = stile * 64;
    const int tid   = threadIdx.x;
    const int tk    = tid & 15;            // k-dim thread coord (within a wave -> shfl merge)
    const int ts    = tid >> 4;            // s-dim thread coord

    const float* Abase = centers + (size_t)l * KNUM * DNUM;
    const float* Hbase = h + (size_t)lb * DNUM * SNUM;   // [D][S] row-major per (l,b)

    const int a_kk = tid >> 2;             // 0..63
    const int a_dp = (tid & 3) * 8;        // 0,8,16,24
    const int b_dr = tid >> 3;             // 0..31
    const int b_sp = (tid & 7) * 8;        // 0..56

    // per-thread running top-2 (over this thread's own k subset), per column j
    float r1[4], r2[4];
    int   rk1[4], rk2[4];
#pragma unroll
    for (int j = 0; j < 4; ++j) { r1[j] = FLT_MAX; r2[j] = FLT_MAX; rk1[j] = 0; rk2[j] = 0; }

    for (int kb = 0; kb < KPAD; kb += 64) {
        float acc[4][4];
#pragma unroll
        for (int i = 0; i < 4; ++i)
#pragma unroll
            for (int j = 0; j < 4; ++j) acc[i][j] = 0.f;

        for (int d0 = 0; d0 < DNUM; d0 += 32) {
            // stage A chunk (64 k x 32 d), transposed to [d][k]
            {
                int kg = kb + a_kk;
                float4 v0 = make_float4(0.f,0.f,0.f,0.f), v1 = v0;
                if (kg < KNUM) {
                    const float* p = Abase + (size_t)kg * DNUM + d0 + a_dp;
                    v0 = *(const float4*)p;
                    v1 = *(const float4*)(p + 4);
                }
                At[a_dp+0][a_kk] = v0.x; At[a_dp+1][a_kk] = v0.y;
                At[a_dp+2][a_kk] = v0.z; At[a_dp+3][a_kk] = v0.w;
                At[a_dp+4][a_kk] = v1.x; At[a_dp+5][a_kk] = v1.y;
                At[a_dp+6][a_kk] = v1.z; At[a_dp+7][a_kk] = v1.w;
            }
            // stage B chunk (32 d x 64 s)
            {
                const float* p = Hbase + (size_t)(d0 + b_dr) * SNUM + s0 + b_sp;
                float4 v0 = (s0 + b_sp     < SNUM) ? *(const float4*)p       : make_float4(0.f,0.f,0.f,0.f);
                float4 v1 = (s0 + b_sp + 4 < SNUM) ? *(const float4*)(p + 4) : make_float4(0.f,0.f,0.f,0.f);
                *(float4*)&Bt[b_dr][b_sp]     = v0;
                *(float4*)&Bt[b_dr][b_sp + 4] = v1;
            }
            __syncthreads();
#pragma unroll
            for (int dd = 0; dd < 32; ++dd) {
                float4 av = *(const float4*)&At[dd][tk * 4];
                float4 bv = *(const float4*)&Bt[dd][ts * 4];
                float a[4]  = {av.x, av.y, av.z, av.w};
                float bbv[4] = {bv.x, bv.y, bv.z, bv.w};
#pragma unroll
                for (int i = 0; i < 4; ++i)
#pragma unroll
                    for (int j = 0; j < 4; ++j)
                        acc[i][j] = fmaf(a[i], bbv[j], acc[i][j]);
            }
            __syncthreads();
        }

        // epilogue: scores for this k-chunk -> insert into per-thread top-2
#pragma unroll
        for (int i = 0; i < 4; ++i) {
            int kg = kb + tk * 4 + i;
            float c2v = (kg < KNUM) ? c2g[l * KNUM + kg] : FLT_MAX;
#pragma unroll
            for (int j = 0; j < 4; ++j) {
                float sc = (kg < KNUM) ? (c2v - 2.f * acc[i][j]) : FLT_MAX;
                if (sc < r1[j])      { r2[j] = r1[j]; rk2[j] = rk1[j]; r1[j] = sc; rk1[j] = kg; }
                else if (sc < r2[j]) { r2[j] = sc; rk2[j] = kg; }
            }
        }
    }

    // cross-lane merge over the 16 tk lanes (within one wave), then owner writes
#pragma unroll
    for (int j = 0; j < 4; ++j) {
        float b1 = r1[j], b2 = r2[j];
        int   k1 = rk1[j], k2 = rk2[j];
#pragma unroll
        for (int m = 1; m <= 8; m <<= 1) {
            float o1 = __shfl_xor(b1, m), o2 = __shfl_xor(b2, m);
            int  ok1 = __shfl_xor(k1, m), ok2 = __shfl_xor(k2, m);
            bool take = (o1 < b1) || (o1 == b1 && ok1 < k1);
            float n1 = take ? o1 : b1;  int nk1 = take ? ok1 : k1;
            float c1s = take ? b1 : o1; int c1k = take ? k1 : ok1;
            float c2s = take ? o2 : b2; int c2k = take ? ok2 : k2;
            bool t2 = (c2s < c1s) || (c2s == c1s && c2k < c1k);
            b1 = n1; k1 = nk1;
            b2 = t2 ? c2s : c1s;
            k2 = t2 ? c2k : c1k;
        }
        if (tk == 0) {
            int sg = s0 + ts * 4 + j;
            if (sg < SNUM) {
                int tok = k1;
                if (b2 - b1 < 0.5f) {
                    // near-tie: rescore both candidates in fp64 (matches f64-exact argmin)
                    const float* c1p = Abase + (size_t)k1 * DNUM;
                    const float* c2p = Abase + (size_t)k2 * DNUM;
                    double xc1 = 0.0, cc1 = 0.0, xc2 = 0.0, cc2 = 0.0;
                    for (int d = 0; d < DNUM; ++d) {
                        double x  = (double)Hbase[(size_t)d * SNUM + sg];
                        double ca = (double)c1p[d];
                        double cb = (double)c2p[d];
                        xc1 += ca * x; cc1 += ca * ca;
                        xc2 += cb * x; cc2 += cb * cb;
                    }
                    double e1 = cc1 - 2.0 * xc1, e2 = cc2 - 2.0 * xc2;
                    if (e2 < e1 || (e2 == e1 && k2 < k1)) tok = k2;
                }
                out_tokens_f[((size_t)bi * SNUM + sg) * LNUM + l] = (float)tok;
                ws_tokens[((size_t)l * BNUM + bi) * SNUM + sg]    = tok;
            }
        }
    }
}

// ---------------- P[l] = centers[l] @ W[l] + b[l]  (K x KT per layer) ----------------
__global__ __launch_bounds__(256, 4)
void proj_kernel(const float* __restrict__ centers, const float* __restrict__ W,
                 const float* __restrict__ bvec, float* __restrict__ P) {
    __shared__ float At[32][68];
    __shared__ float Wt[32][68];
    const int jt = blockIdx.x;   // 0..7
    const int kt = blockIdx.y;   // 0..15
    const int l  = blockIdx.z;   // 0..3
    const int j0 = jt * 64, k0 = kt * 64;
    const int tid = threadIdx.x;
    const int ts = tid & 15;     // column coord (coalesced writes)
    const int tk = tid >> 4;     // row coord

    const float* Abase = centers + (size_t)l * KNUM * DNUM;
    const float* Wbase = W + (size_t)l * DNUM * KTNUM;

    const int a_kk = tid >> 2, a_dp = (tid & 3) * 8;
    const int w_dr = tid >> 3, w_jp = (tid & 7) * 8;

    float acc[4][4];
#pragma unroll
    for (int i = 0; i < 4; ++i)
#pragma unroll
        for (int j = 0; j < 4; ++j) acc[i][j] = 0.f;

    for (int d0 = 0; d0 < DNUM; d0 += 32) {
        {
            int kg = k0 + a_kk;
            float4 v0 = make_float4(0.f,0.f,0.f,0.f), v1 = v0;
            if (kg < KNUM) {
                const float* p = Abase + (size_t)kg * DNUM + d0 + a_dp;
                v0 = *(const float4*)p;
                v1 = *(const float4*)(p + 4);
            }
            At[a_dp+0][a_kk] = v0.x; At[a_dp+1][a_kk] = v0.y;
            At[a_dp+2][a_kk] = v0.z; At[a_dp+3][a_kk] = v0.w;
            At[a_dp+4][a_kk] = v1.x; At[a_dp+5][a_kk] = v1.y;
            At[a_dp+6][a_kk] = v1.z; At[a_dp+7][a_kk] = v1.w;
        }
        {
            const float* p = Wbase + (size_t)(d0 + w_dr) * KTNUM + j0 + w_jp;
            *(float4*)&Wt[w_dr][w_jp]     = *(const float4*)p;
            *(float4*)&Wt[w_dr][w_jp + 4] = *(const float4*)(p + 4);
        }
        __syncthreads();
#pragma unroll
        for (int dd = 0; dd < 32; ++dd) {
            float4 av = *(const float4*)&At[dd][tk * 4];
            float4 bv = *(const float4*)&Wt[dd][ts * 4];
            float a[4]  = {av.x, av.y, av.z, av.w};
            float bb[4] = {bv.x, bv.y, bv.z, bv.w};
#pragma unroll
            for (int i = 0; i < 4; ++i)
#pragma unroll
                for (int j = 0; j < 4; ++j)
                    acc[i][j] = fmaf(a[i], bb[j], acc[i][j]);
        }
        __syncthreads();
    }

    float4 bb4 = *(const float4*)&bvec[l * KTNUM + j0 + ts * 4];
#pragma unroll
    for (int i = 0; i < 4; ++i) {
        int r = k0 + tk * 4 + i;
        if (r < KNUM) {
            float4 o;
            o.x = acc[i][0] + bb4.x; o.y = acc[i][1] + bb4.y;
            o.z = acc[i][2] + bb4.z; o.w = acc[i][3] + bb4.w;
            *(float4*)&P[((size_t)l * KNUM + r) * KTNUM + j0 + ts * 4] = o;
        }
    }
}

// ---------------- gather: out[b][s][l][:] = P[l][tok] ----------------
__global__ void gather_kernel(const float* __restrict__ P, const int* __restrict__ ws_tokens,
                              float* __restrict__ out_embs) {
    __shared__ int toks[LNUM];
    int bs  = blockIdx.x;                 // 0..B*S-1
    int bi  = bs / SNUM;
    int s   = bs % SNUM;
    int tid = threadIdx.x;
    if (tid < LNUM) toks[tid] = ws_tokens[((size_t)tid * BNUM + bi) * SNUM + s];
    __syncthreads();
    const float4* P4 = (const float4*)P;
    float4* O4 = (float4*)out_embs + (size_t)bs * (LNUM * KTNUM / 4);
#pragma unroll
    for (int r = 0; r < 2; ++r) {
        int idx = tid + r * 256;          // 0..511
        int l   = idx >> 7;               // / (KT/4)
        int j4  = idx & 127;
        O4[idx] = P4[(((size_t)l * KNUM + toks[l]) * KTNUM >> 2) + j4];
    }
}

extern "C" void kernel_launch(void* const* d_in, const int* in_sizes, int n_in,
                              void* d_out, int out_size, void* d_ws, size_t ws_size,
                              hipStream_t stream) {
    const float* h       = (const float*)d_in[0];
    const float* centers = (const float*)d_in[1];
    const float* W       = (const float*)d_in[2];
    const float* b       = (const float*)d_in[3];

    float* out        = (float*)d_out;
    float* out_tokens = out;                                  // B*S*L floats (token values)
    float* out_embs   = out + (size_t)BNUM * SNUM * LNUM;     // B*S*L*KT floats

    char*  ws        = (char*)d_ws;
    int*   ws_tokens = (int*)ws;                              // 64000 ints   @ 0
    float* c2        = (float*)(ws + 256 * 1024);             // 4000 floats  @ 256KB
    float* P         = (float*)(ws + 512 * 1024);             // 2.048M floats @ 512KB

    c2_kernel<<<dim3(LNUM * KNUM), dim3(64), 0, stream>>>(centers, c2);
    token_kernel<<<dim3(16, 64), dim3(256), 0, stream>>>(h, centers, c2, out_tokens, ws_tokens);
    proj_kernel<<<dim3(8, 16, LNUM), dim3(256), 0, stream>>>(centers, W, b, P);
    gather_kernel<<<dim3(BNUM * SNUM), dim3(256), 0, stream>>>(P, ws_tokens, out_embs);
}

// Round 3
// 615.091 us; speedup vs baseline: 2.9026x; 2.9026x over previous
//
#include <hip/hip_runtime.h>
#include <hip/hip_bf16.h>
#include <cfloat>

#define LNUM 4
#define BNUM 16
#define DNUM 768
#define SNUM 1000
#define KNUM 1000
#define KPAD 1024
#define KTNUM 512

typedef __attribute__((ext_vector_type(8))) short s16x8;
typedef __attribute__((ext_vector_type(4))) float f32x4;

__device__ __forceinline__ unsigned short bfb(float x) {
    return __builtin_bit_cast(unsigned short, (__bf16)x);
}
__device__ __forceinline__ void ins4(unsigned int& t0, unsigned int& t1,
                                     unsigned int& t2, unsigned int& t3, unsigned int key) {
    if (key < t3) {
        bool b2 = key < t2, b1 = key < t1, b0 = key < t0;
        t3 = b2 ? t2 : key;
        t2 = b1 ? t1 : (b2 ? key : t2);
        t1 = b0 ? t0 : (b1 ? key : t1);
        t0 = b0 ? key : t0;
    }
}
__device__ __forceinline__ float keyscore(unsigned int key) {
    unsigned int v = key & ~1023u;
    unsigned int u = (v & 0x80000000u) ? (v ^ 0x80000000u) : ~v;
    return __builtin_bit_cast(float, u);
}

// ---------------- zero tie counter ----------------
__global__ void zero_kernel(int* cnt) { *cnt = 0; }

// ---------------- centers fp32 -> bf16, padded to KPAD rows ----------------
__global__ void prep_kernel(const float* __restrict__ centers, unsigned short* __restrict__ cb_hi) {
    size_t i8 = ((size_t)blockIdx.x * 256 + threadIdx.x) * 8;
    int l  = (int)(i8 / ((size_t)KPAD * DNUM));
    size_t rem = i8 % ((size_t)KPAD * DNUM);
    int kk = (int)(rem / DNUM);
    int d  = (int)(rem % DNUM);
    s16x8 vh = 0;
    if (kk < KNUM) {
        const float* src = centers + ((size_t)l * KNUM + kk) * DNUM + d;
        float4 x0 = *(const float4*)src;
        float4 x1 = *(const float4*)(src + 4);
        float xs[8] = {x0.x, x0.y, x0.z, x0.w, x1.x, x1.y, x1.z, x1.w};
#pragma unroll
        for (int i = 0; i < 8; ++i) vh[i] = (short)bfb(xs[i]);
    }
    *(s16x8*)&cb_hi[i8] = vh;
}

// ---------------- c2 = ||c||^2 (padded rows -> huge) ----------------
__global__ void c2_kernel(const float* __restrict__ centers, float* __restrict__ c2p) {
    int row  = blockIdx.x;          // 0..L*KPAD-1
    int l    = row >> 10;
    int kk   = row & (KPAD - 1);
    int lane = threadIdx.x;
    if (kk >= KNUM) { if (lane == 0) c2p[row] = 3.0e38f; return; }
    const float* cr = centers + ((size_t)l * KNUM + kk) * DNUM;
    float s = 0.f;
    for (int d = lane; d < DNUM; d += 64) s += cr[d] * cr[d];
#pragma unroll
    for (int m = 32; m >= 1; m >>= 1) s += __shfl_xor(s, m);
    if (lane == 0) c2p[row] = s;
}

// ---------------- token kernel: 16x16x32 bf16 MFMA (verified layout), linear LDS ----------------
// block tile 256k x 128s, 4 waves; wave w owns k rows [w*64, w*64+64), all 128 s cols
__global__ __launch_bounds__(256, 2)
void token_kernel(const float* __restrict__ h, const unsigned short* __restrict__ cb_hi,
                  const float* __restrict__ c2p, float* __restrict__ out_tokens_f,
                  int* __restrict__ ws_tokens, int* __restrict__ tie_cnt,
                  int4* __restrict__ tie_buf) {
    __shared__ unsigned short A_sh[256 * 64];      // [k][d] linear, 32 KB
    __shared__ unsigned short B_sh[128 * 64];      // [s][d] linear, 16 KB
    __shared__ float c2_sh[256];
    __shared__ unsigned int tk_lds[4][128][4];     // 8 KB

    const int tid  = threadIdx.x;
    const int lane = tid & 63;
    const int w    = tid >> 6;
    const int ln15 = lane & 15;
    const int lg   = lane >> 4;          // 0..3  (k-group within fragment)

    const int stile = blockIdx.x;        // 0..7
    const int lb    = blockIdx.y;        // l*16+b
    const int l     = lb >> 4;
    const int bi    = lb & 15;
    const int s0    = stile * 128;

    const unsigned short* cbl = cb_hi + (size_t)l * KPAD * DNUM;
    const float* Hb = h + (size_t)lb * DNUM * SNUM;

    unsigned int tk4[8][4];
#pragma unroll
    for (int fj = 0; fj < 8; ++fj)
#pragma unroll
        for (int r = 0; r < 4; ++r) tk4[fj][r] = 0xFFFFFFFFu;

    for (int kb = 0; kb < KPAD; kb += 256) {
        f32x4 acc[4][8];
#pragma unroll
        for (int fi = 0; fi < 4; ++fi)
#pragma unroll
            for (int fj = 0; fj < 8; ++fj)
#pragma unroll
                for (int r = 0; r < 4; ++r) acc[fi][fj][r] = 0.f;

        for (int c = 0; c < 12; ++c) {
            const int d0 = c * 64;
            __syncthreads();
            // ---- stage A: 256 k-rows x 64 d (int4 = 8 bf16), linear
            {
                const int slot = tid & 7;
                const int rb   = tid >> 3;     // 0..31
#pragma unroll
                for (int j = 0; j < 8; ++j) {
                    int krow = rb + 32 * j;
                    *(int4*)&A_sh[krow * 64 + slot * 8] =
                        *(const int4*)(cbl + (size_t)(kb + krow) * DNUM + d0 + slot * 8);
                }
            }
            // ---- stage B: transpose+convert h [d][s] -> B_sh [s][d], linear
            {
#pragma unroll
                for (int p = 0; p < 4; ++p) {
                    int dp = ((tid >> 5) << 1) + (p << 4);   // even d in [0,64)
                    int s4 = (tid & 31) << 2;                // 0..124
                    int sg = s0 + s4;
                    float4 f0, f1;
                    if (sg < SNUM) {
                        f0 = *(const float4*)(Hb + (size_t)(d0 + dp) * SNUM + sg);
                        f1 = *(const float4*)(Hb + (size_t)(d0 + dp + 1) * SNUM + sg);
                    } else {
                        f0 = make_float4(0.f, 0.f, 0.f, 0.f); f1 = f0;
                    }
                    float a0[4] = {f0.x, f0.y, f0.z, f0.w};
                    float a1[4] = {f1.x, f1.y, f1.z, f1.w};
#pragma unroll
                    for (int ii = 0; ii < 4; ++ii) {
                        unsigned int pk = (unsigned int)bfb(a0[ii]) | ((unsigned int)bfb(a1[ii]) << 16);
                        *(unsigned int*)&B_sh[(s4 + ii) * 64 + dp] = pk;
                    }
                }
            }
            if (c == 0) c2_sh[tid] = c2p[l * KPAD + kb + tid];
            __syncthreads();
            // ---- compute: 2 K-steps x (4 x 8) MFMA
#pragma unroll
            for (int t = 0; t < 2; ++t) {
                const int doff = 32 * t + 8 * lg;
                s16x8 av[4], bv[8];
#pragma unroll
                for (int fi = 0; fi < 4; ++fi)
                    av[fi] = *(const s16x8*)&A_sh[(w * 64 + fi * 16 + ln15) * 64 + doff];
#pragma unroll
                for (int fj = 0; fj < 8; ++fj)
                    bv[fj] = *(const s16x8*)&B_sh[(fj * 16 + ln15) * 64 + doff];
#pragma unroll
                for (int fi = 0; fi < 4; ++fi)
#pragma unroll
                    for (int fj = 0; fj < 8; ++fj)
                        acc[fi][fj] = __builtin_amdgcn_mfma_f32_16x16x32_bf16(av[fi], bv[fj], acc[fi][fj], 0, 0, 0);
            }
        }
        // ---- epilogue: scores -> packed keys -> top-4 insert
#pragma unroll
        for (int fi = 0; fi < 4; ++fi) {
#pragma unroll
            for (int r = 0; r < 4; ++r) {
                const int klocal = w * 64 + fi * 16 + 4 * lg + r;   // C/D row = 4*(lane>>4)+reg
                const float c2v = c2_sh[klocal];
                const unsigned int kg = (unsigned int)(kb + klocal);
#pragma unroll
                for (int fj = 0; fj < 8; ++fj) {
                    float sc = fmaf(-2.f, acc[fi][fj][r], c2v);
                    unsigned int u = __builtin_bit_cast(unsigned int, sc);
                    u ^= 0x80000000u | (unsigned int)((int)u >> 31);
                    unsigned int key = (u & ~1023u) | kg;
                    ins4(tk4[fj][0], tk4[fj][1], tk4[fj][2], tk4[fj][3], key);
                }
            }
        }
    }
    // ---- intra-wave merge across the 4 lane-groups (same columns)
#pragma unroll
    for (int m = 16; m <= 32; m <<= 1) {
#pragma unroll
        for (int fj = 0; fj < 8; ++fj) {
            unsigned int o0 = (unsigned int)__shfl_xor((int)tk4[fj][0], m);
            unsigned int o1 = (unsigned int)__shfl_xor((int)tk4[fj][1], m);
            unsigned int o2 = (unsigned int)__shfl_xor((int)tk4[fj][2], m);
            unsigned int o3 = (unsigned int)__shfl_xor((int)tk4[fj][3], m);
            ins4(tk4[fj][0], tk4[fj][1], tk4[fj][2], tk4[fj][3], o0);
            ins4(tk4[fj][0], tk4[fj][1], tk4[fj][2], tk4[fj][3], o1);
            ins4(tk4[fj][0], tk4[fj][1], tk4[fj][2], tk4[fj][3], o2);
            ins4(tk4[fj][0], tk4[fj][1], tk4[fj][2], tk4[fj][3], o3);
        }
    }
    if (lg == 0) {
#pragma unroll
        for (int fj = 0; fj < 8; ++fj) {
            uint4 v = make_uint4(tk4[fj][0], tk4[fj][1], tk4[fj][2], tk4[fj][3]);
            *(uint4*)&tk_lds[w][fj * 16 + ln15][0] = v;
        }
    }
    __syncthreads();
    // ---- cross-wave merge + write (one thread per column)
    if (tid < 128) {
        const int col = tid;
        uint4 v0 = *(const uint4*)&tk_lds[0][col][0];
        unsigned int t0 = v0.x, t1 = v0.y, t2 = v0.z, t3 = v0.w;
#pragma unroll
        for (int ww = 1; ww < 4; ++ww) {
            uint4 v = *(const uint4*)&tk_lds[ww][col][0];
            ins4(t0, t1, t2, t3, v.x);
            ins4(t0, t1, t2, t3, v.y);
            ins4(t0, t1, t2, t3, v.z);
            ins4(t0, t1, t2, t3, v.w);
        }
        const int sg = s0 + col;
        if (sg < SNUM) {
            const int tok = (int)(t0 & 1023u);
            out_tokens_f[((size_t)bi * SNUM + sg) * LNUM + l] = (float)tok;
            ws_tokens[((size_t)l * BNUM + bi) * SNUM + sg] = tok;
            if (keyscore(t1) - keyscore(t0) < 4.0f) {
                int idx = atomicAdd(tie_cnt, 1);
                if (idx < 65536) {
                    tie_buf[idx] = make_int4((lb << 10) | sg,
                                             (int)((t0 & 1023u) | ((t1 & 1023u) << 16)),
                                             (int)((t2 & 1023u) | ((t3 & 1023u) << 16)), 0);
                }
            }
        }
    }
}

// ---------------- fp64 rescore of near-ties ----------------
__global__ void rescore_kernel(const float* __restrict__ h, const float* __restrict__ centers,
                               const int* __restrict__ tie_cnt, const int4* __restrict__ tie_buf,
                               float* __restrict__ out_tokens_f, int* __restrict__ ws_tokens) {
    const int lane = threadIdx.x & 63;
    const int wave_id = blockIdx.x * 4 + (threadIdx.x >> 6);
    int cnt = *tie_cnt;
    if (cnt > 65536) cnt = 65536;
    for (int e = wave_id; e < cnt; e += 256 * 4) {
        int4 ent = tie_buf[e];
        const int sg = ent.x & 1023, lb = ent.x >> 10;
        const int l = lb >> 4, bi = lb & 15;
        const int g = lane >> 4;
        int kc = (g == 0) ? (ent.y & 0xFFFF) : (g == 1) ? ((ent.y >> 16) & 0xFFFF)
               : (g == 2) ? (ent.z & 0xFFFF) : ((ent.z >> 16) & 0xFFFF);
        const float* cp = centers + ((size_t)l * KNUM + kc) * DNUM;
        const float* xp = h + (size_t)lb * DNUM * SNUM + sg;
        double xc = 0.0, cc = 0.0;
        for (int d = (lane & 15); d < DNUM; d += 16) {
            double cv = (double)cp[d];
            double xv = (double)xp[(size_t)d * SNUM];
            xc = fma(cv, xv, xc);
            cc = fma(cv, cv, cc);
        }
        double sc = cc - 2.0 * xc;
#pragma unroll
        for (int m = 1; m <= 8; m <<= 1) sc += __shfl_xor(sc, m);
        double s0 = __shfl(sc, 0), s1 = __shfl(sc, 16), s2 = __shfl(sc, 32), s3 = __shfl(sc, 48);
        if (lane == 0) {
            int k0 = ent.y & 0xFFFF, k1 = (ent.y >> 16) & 0xFFFF;
            int k2 = ent.z & 0xFFFF, k3 = (ent.z >> 16) & 0xFFFF;
            double bs = s0; int bk = k0;
            if (s1 < bs || (s1 == bs && k1 < bk)) { bs = s1; bk = k1; }
            if (s2 < bs || (s2 == bs && k2 < bk)) { bs = s2; bk = k2; }
            if (s3 < bs || (s3 == bs && k3 < bk)) { bs = s3; bk = k3; }
            out_tokens_f[((size_t)bi * SNUM + sg) * LNUM + l] = (float)bk;
            ws_tokens[((size_t)l * BNUM + bi) * SNUM + sg] = bk;
        }
    }
}

// ---------------- proj (R1 fp32 version, verified): P[l] = centers @ W + b ----------------
__global__ __launch_bounds__(256, 4)
void proj_kernel(const float* __restrict__ centers, const float* __restrict__ W,
                 const float* __restrict__ bvec, float* __restrict__ P) {
    __shared__ float At[32][68];
    __shared__ float Wt[32][68];
    const int jt = blockIdx.x;   // 0..7
    const int kt = blockIdx.y;   // 0..15
    const int l  = blockIdx.z;   // 0..3
    const int j0 = jt * 64, k0 = kt * 64;
    const int tid = threadIdx.x;
    const int ts = tid & 15;
    const int tk = tid >> 4;

    const float* Abase = centers + (size_t)l * KNUM * DNUM;
    const float* Wbase = W + (size_t)l * DNUM * KTNUM;

    const int a_kk = tid >> 2, a_dp = (tid & 3) * 8;
    const int w_dr = tid >> 3, w_jp = (tid & 7) * 8;

    float acc[4][4];
#pragma unroll
    for (int i = 0; i < 4; ++i)
#pragma unroll
        for (int j = 0; j < 4; ++j) acc[i][j] = 0.f;

    for (int d0 = 0; d0 < DNUM; d0 += 32) {
        {
            int kg = k0 + a_kk;
            float4 v0 = make_float4(0.f,0.f,0.f,0.f), v1 = v0;
            if (kg < KNUM) {
                const float* p = Abase + (size_t)kg * DNUM + d0 + a_dp;
                v0 = *(const float4*)p;
                v1 = *(const float4*)(p + 4);
            }
            At[a_dp+0][a_kk] = v0.x; At[a_dp+1][a_kk] = v0.y;
            At[a_dp+2][a_kk] = v0.z; At[a_dp+3][a_kk] = v0.w;
            At[a_dp+4][a_kk] = v1.x; At[a_dp+5][a_kk] = v1.y;
            At[a_dp+6][a_kk] = v1.z; At[a_dp+7][a_kk] = v1.w;
        }
        {
            const float* p = Wbase + (size_t)(d0 + w_dr) * KTNUM + j0 + w_jp;
            *(float4*)&Wt[w_dr][w_jp]     = *(const float4*)p;
            *(float4*)&Wt[w_dr][w_jp + 4] = *(const float4*)(p + 4);
        }
        __syncthreads();
#pragma unroll
        for (int dd = 0; dd < 32; ++dd) {
            float4 av = *(const float4*)&At[dd][tk * 4];
            float4 bv = *(const float4*)&Wt[dd][ts * 4];
            float a[4]  = {av.x, av.y, av.z, av.w};
            float bb[4] = {bv.x, bv.y, bv.z, bv.w};
#pragma unroll
            for (int i = 0; i < 4; ++i)
#pragma unroll
                for (int j = 0; j < 4; ++j)
                    acc[i][j] = fmaf(a[i], bb[j], acc[i][j]);
        }
        __syncthreads();
    }

    float4 bb4 = *(const float4*)&bvec[l * KTNUM + j0 + ts * 4];
#pragma unroll
    for (int i = 0; i < 4; ++i) {
        int r = k0 + tk * 4 + i;
        if (r < KNUM) {
            float4 o;
            o.x = acc[i][0] + bb4.x; o.y = acc[i][1] + bb4.y;
            o.z = acc[i][2] + bb4.z; o.w = acc[i][3] + bb4.w;
            *(float4*)&P[((size_t)l * KNUM + r) * KTNUM + j0 + ts * 4] = o;
        }
    }
}

// ---------------- gather: out[b][s][l][:] = P[l][tok] ----------------
__global__ void gather_kernel(const float* __restrict__ P, const int* __restrict__ ws_tokens,
                              float* __restrict__ out_embs) {
    __shared__ int toks[LNUM];
    int bs  = blockIdx.x;
    int bi  = bs / SNUM;
    int s   = bs % SNUM;
    int tid = threadIdx.x;
    if (tid < LNUM) toks[tid] = ws_tokens[((size_t)tid * BNUM + bi) * SNUM + s];
    __syncthreads();
    const float4* P4 = (const float4*)P;
    float4* O4 = (float4*)out_embs + (size_t)bs * (LNUM * KTNUM / 4);
#pragma unroll
    for (int r = 0; r < 2; ++r) {
        int idx = tid + r * 256;
        int l   = idx >> 7;
        int j4  = idx & 127;
        O4[idx] = P4[(((size_t)l * KNUM + toks[l]) * KTNUM >> 2) + j4];
    }
}

extern "C" void kernel_launch(void* const* d_in, const int* in_sizes, int n_in,
                              void* d_out, int out_size, void* d_ws, size_t ws_size,
                              hipStream_t stream) {
    const float* h       = (const float*)d_in[0];
    const float* centers = (const float*)d_in[1];
    const float* W       = (const float*)d_in[2];
    const float* b       = (const float*)d_in[3];

    float* out        = (float*)d_out;
    float* out_tokens = out;
    float* out_embs   = out + (size_t)BNUM * SNUM * LNUM;

    char* ws = (char*)d_ws;
    int*            ws_tokens = (int*)ws;                              // 256 KB
    float*          c2p       = (float*)(ws + (256 << 10));            // 16 KB
    int*            tie_cnt   = (int*)(ws + (288 << 10));
    int4*           tie_buf   = (int4*)(ws + (320 << 10));             // 1 MB
    float*          P         = (float*)(ws + (1536 << 10));           // 8.19 MB
    unsigned short* cb_hi     = (unsigned short*)(ws + (10496 << 10)); // 6.29 MB

    zero_kernel<<<1, 1, 0, stream>>>(tie_cnt);
    prep_kernel<<<dim3(1536), dim3(256), 0, stream>>>(centers, cb_hi);
    c2_kernel<<<dim3(LNUM * KPAD), dim3(64), 0, stream>>>(centers, c2p);
    token_kernel<<<dim3(8, 64), dim3(256), 0, stream>>>(h, cb_hi, c2p, out_tokens,
                                                        ws_tokens, tie_cnt, tie_buf);
    rescore_kernel<<<dim3(256), dim3(256), 0, stream>>>(h, centers, tie_cnt, tie_buf,
                                                        out_tokens, ws_tokens);
    proj_kernel<<<dim3(8, 16, LNUM), dim3(256), 0, stream>>>(centers, W, b, P);
    gather_kernel<<<dim3(BNUM * SNUM), dim3(256), 0, stream>>>(P, ws_tokens, out_embs);
}